// Round 1
// baseline (887.749 us; speedup 1.0000x reference)
//
#include <hip/hip_runtime.h>
#include <hip/hip_bf16.h>

#define NNODES 500000
#define DFEAT  128   // D
// K = 2*D = 256

typedef __attribute__((ext_vector_type(8))) short    bf16x8;   // MFMA A/B frag (4 VGPRs)
typedef __attribute__((ext_vector_type(4))) float    f32x4;    // MFMA C/D frag
typedef __attribute__((ext_vector_type(4))) float    float4v;
typedef __attribute__((ext_vector_type(8))) unsigned short ushort8;

static __device__ __forceinline__ unsigned short f2bf(float f) {
    unsigned u = __builtin_bit_cast(unsigned, f);
    unsigned r = u + 0x7FFF + ((u >> 16) & 1);   // round-to-nearest-even
    return (unsigned short)(r >> 16);
}

// ---- feature fp32 -> bf16, vectorized (32B in / 16B out per iter) ----
__global__ void cvt_bf16_kernel(const float* __restrict__ in,
                                unsigned short* __restrict__ out, int nchunk8) {
    int i = blockIdx.x * blockDim.x + threadIdx.x;
    int stride = gridDim.x * blockDim.x;
    for (; i < nchunk8; i += stride) {
        float4v a = ((const float4v*)in)[2 * i];
        float4v b = ((const float4v*)in)[2 * i + 1];
        ushort8 o;
        o[0] = f2bf(a.x); o[1] = f2bf(a.y); o[2] = f2bf(a.z); o[3] = f2bf(a.w);
        o[4] = f2bf(b.x); o[5] = f2bf(b.y); o[6] = f2bf(b.z); o[7] = f2bf(b.w);
        ((ushort8*)out)[i] = o;
    }
}

// ---- pack W [256][128] fp32 row-major -> bf16 B-fragment layout ----
// chunk c = (kk*8 + n)*64 + lane ; element i -> B[k = kk*32 + (lane>>4)*8 + i]
//                                               [col = n*16 + (lane&15)]
__global__ void pack_w_kernel(const float* __restrict__ W,
                              unsigned short* __restrict__ Wp) {
    int c = blockIdx.x * blockDim.x + threadIdx.x;
    if (c >= 4096) return;
    int l  = c & 63;
    int t  = c >> 6;          // kk*8 + n
    int kk = t >> 3, n = t & 7;
    ushort8 o;
    #pragma unroll
    for (int i = 0; i < 8; ++i) {
        int k   = kk * 32 + (l >> 4) * 8 + i;
        int col = n * 16 + (l & 15);
        o[i] = f2bf(W[k * 128 + col]);
    }
    ((ushort8*)Wp)[c] = o;
}

// ---- one hop: out = [state | feat[idx]] @ W + b  (ReLU if FINAL) ----
// block = 256 threads (4 waves), each wave owns 32 rows (2x 16-row MFMA tiles),
// all 128 output cols. W (64KB bf16, pre-packed) staged in LDS.
template<int FINAL>
__global__ __launch_bounds__(256, 2) void hop_kernel(
    const unsigned short* __restrict__ state,   // [N][128] bf16
    const unsigned short* __restrict__ feat,    // [N][128] bf16
    const int*            __restrict__ idx,     // [N]
    const unsigned short* __restrict__ Wp,      // packed, 32768 bf16
    const float*          __restrict__ bias,    // [128]
    unsigned short*       __restrict__ out_b,   // bf16 out (hops 0,1)
    float*                __restrict__ out_f)   // fp32 out (final hop)
{
    __shared__ __align__(16) unsigned short Wl[32768];   // 64 KB
    int t = threadIdx.x;
    for (int j = t; j < 4096; j += 256)
        ((ushort8*)Wl)[j] = ((const ushort8*)Wp)[j];
    __syncthreads();

    int wave = t >> 6, lane = t & 63;
    int rowtile = blockIdx.x * 128 + wave * 32;
    int ar  = lane & 15;          // A-row within 16-row tile
    int sub = (lane >> 4) * 8;    // k sub-offset (elements) within 32-chunk

    int r0 = rowtile + ar, r1 = r0 + 16;
    int cr0 = min(r0, NNODES - 1), cr1 = min(r1, NNODES - 1);
    int g0 = idx[cr0], g1 = idx[cr1];

    const unsigned short* s0 = state + (size_t)cr0 * 128 + sub;
    const unsigned short* s1 = state + (size_t)cr1 * 128 + sub;
    const unsigned short* f0 = feat  + (size_t)g0  * 128 + sub;
    const unsigned short* f1 = feat  + (size_t)g1  * 128 + sub;

    f32x4 acc[2][8];
    #pragma unroll
    for (int r = 0; r < 2; ++r)
        #pragma unroll
        for (int n = 0; n < 8; ++n)
            acc[r][n] = f32x4{0.f, 0.f, 0.f, 0.f};

    #pragma unroll
    for (int kk = 0; kk < 8; ++kk) {
        const unsigned short* p0 = (kk < 4) ? s0 + kk * 32 : f0 + (kk - 4) * 32;
        const unsigned short* p1 = (kk < 4) ? s1 + kk * 32 : f1 + (kk - 4) * 32;
        bf16x8 a0 = *(const bf16x8*)p0;
        bf16x8 a1 = *(const bf16x8*)p1;
        #pragma unroll
        for (int n = 0; n < 8; ++n) {
            bf16x8 b = *(const bf16x8*)&Wl[(size_t)((kk * 8 + n) * 64 + lane) * 8];
            acc[0][n] = __builtin_amdgcn_mfma_f32_16x16x32_bf16(a0, b, acc[0][n], 0, 0, 0);
            acc[1][n] = __builtin_amdgcn_mfma_f32_16x16x32_bf16(a1, b, acc[1][n], 0, 0, 0);
        }
    }

    // epilogue: C/D layout col = lane&15, row = (lane>>4)*4 + i   [m89-verified]
    int crow = (lane >> 4) * 4;
    int ccol = lane & 15;
    #pragma unroll
    for (int n = 0; n < 8; ++n) {
        float bv = bias[n * 16 + ccol];
        #pragma unroll
        for (int r = 0; r < 2; ++r) {
            int rb = rowtile + r * 16 + crow;
            #pragma unroll
            for (int i = 0; i < 4; ++i) {
                int row = rb + i;
                if (row < NNODES) {
                    float v = acc[r][n][i] + bv;
                    size_t off = (size_t)row * 128 + n * 16 + ccol;
                    if (FINAL) out_f[off] = fmaxf(v, 0.f);
                    else       out_b[off] = f2bf(v);
                }
            }
        }
    }
}

extern "C" void kernel_launch(void* const* d_in, const int* in_sizes, int n_in,
                              void* d_out, int out_size, void* d_ws, size_t ws_size,
                              hipStream_t stream) {
    const float* feature = (const float*)d_in[0];   // [N][128] fp32
    const float* W       = (const float*)d_in[1];   // [256][128] fp32
    const float* bias    = (const float*)d_in[2];   // [128] fp32
    const int*   idx     = (const int*)d_in[3];     // [3][N] int32

    // workspace layout (needs ~256.07 MB):
    //   Wp        : ws + 0        (64 KB, packed bf16 W)
    //   feature_b : ws + 64 KB    (128 MB bf16 feature table)
    //   s2        : ws + 64KB+128MB (128 MB bf16 hop-1 state)
    // hop-0 state output lives in d_out's first 128 MB (d_out is 256 MB fp32).
    unsigned short* Wp        = (unsigned short*)d_ws;
    unsigned short* feature_b = (unsigned short*)((char*)d_ws + 65536);
    unsigned short* s2        = (unsigned short*)((char*)d_ws + 65536 + (size_t)NNODES * 128 * 2);
    unsigned short* s1        = (unsigned short*)d_out;   // scratch inside d_out
    float*          outf      = (float*)d_out;

    const int nchunk8 = NNODES * DFEAT / 8;   // 8,000,000
    cvt_bf16_kernel<<<2048, 256, 0, stream>>>(feature, feature_b, nchunk8);
    pack_w_kernel<<<16, 256, 0, stream>>>(W, Wp);

    const int grid = (NNODES + 127) / 128;    // 3907
    hop_kernel<0><<<grid, 256, 0, stream>>>(feature_b, feature_b, idx,              Wp, bias, s1, nullptr);
    hop_kernel<0><<<grid, 256, 0, stream>>>(s1,        feature_b, idx + NNODES,     Wp, bias, s2, nullptr);
    hop_kernel<1><<<grid, 256, 0, stream>>>(s2,        feature_b, idx + 2 * NNODES, Wp, bias, nullptr, outf);
}

// Round 2
// 758.722 us; speedup vs baseline: 1.1701x; 1.1701x over previous
//
#include <hip/hip_runtime.h>
#include <hip/hip_bf16.h>

#define NNODES 500000
#define DFEAT  128   // D
// K = 2*D = 256

typedef __attribute__((ext_vector_type(8))) short    bf16x8;   // MFMA A/B frag (4 VGPRs)
typedef __attribute__((ext_vector_type(4))) float    f32x4;    // MFMA C/D frag
typedef __attribute__((ext_vector_type(4))) float    float4v;
typedef __attribute__((ext_vector_type(8))) unsigned short ushort8;

static __device__ __forceinline__ unsigned short f2bf(float f) {
    unsigned u = __builtin_bit_cast(unsigned, f);
    unsigned r = u + 0x7FFF + ((u >> 16) & 1);   // round-to-nearest-even
    return (unsigned short)(r >> 16);
}

// ---- feature fp32 -> bf16, vectorized (32B in / 16B out per iter) ----
__global__ void cvt_bf16_kernel(const float* __restrict__ in,
                                unsigned short* __restrict__ out, int nchunk8) {
    int i = blockIdx.x * blockDim.x + threadIdx.x;
    int stride = gridDim.x * blockDim.x;
    for (; i < nchunk8; i += stride) {
        float4v a = ((const float4v*)in)[2 * i];
        float4v b = ((const float4v*)in)[2 * i + 1];
        ushort8 o;
        o[0] = f2bf(a.x); o[1] = f2bf(a.y); o[2] = f2bf(a.z); o[3] = f2bf(a.w);
        o[4] = f2bf(b.x); o[5] = f2bf(b.y); o[6] = f2bf(b.z); o[7] = f2bf(b.w);
        ((ushort8*)out)[i] = o;
    }
}

// ---- pack W [256][128] fp32 row-major -> bf16 B-fragment layout ----
// chunk c = (kk*8 + n)*64 + lane ; element i -> B[k = kk*32 + (lane>>4)*8 + i]
//                                               [col = n*16 + (lane&15)]
__global__ void pack_w_kernel(const float* __restrict__ W,
                              unsigned short* __restrict__ Wp) {
    int c = blockIdx.x * blockDim.x + threadIdx.x;
    if (c >= 4096) return;
    int l  = c & 63;
    int t  = c >> 6;          // kk*8 + n
    int kk = t >> 3, n = t & 7;
    ushort8 o;
    #pragma unroll
    for (int i = 0; i < 8; ++i) {
        int k   = kk * 32 + (l >> 4) * 8 + i;
        int col = n * 16 + (l & 15);
        o[i] = f2bf(W[k * 128 + col]);
    }
    ((ushort8*)Wp)[c] = o;
}

// ---- one hop: out = [state | feat[idx]] @ W + b  (ReLU if FINAL) ----
// block = 512 threads (8 waves), each wave owns 32 rows (2x 16-row MFMA tiles),
// all 128 output cols. W (64KB bf16, pre-packed) staged in LDS.
// 64KB LDS/block -> 2 blocks/CU = 16 waves/CU (4/SIMD) -> 50% occupancy.
template<int FINAL>
__global__ __launch_bounds__(512, 4) void hop_kernel(
    const unsigned short* __restrict__ state,   // [N][128] bf16
    const unsigned short* __restrict__ feat,    // [N][128] bf16
    const int*            __restrict__ idx,     // [N]
    const unsigned short* __restrict__ Wp,      // packed, 32768 bf16
    const float*          __restrict__ bias,    // [128]
    unsigned short*       __restrict__ out_b,   // bf16 out (hops 0,1)
    float*                __restrict__ out_f)   // fp32 out (final hop)
{
    __shared__ __align__(16) unsigned short Wl[32768];   // 64 KB
    int t = threadIdx.x;
    for (int j = t; j < 4096; j += 512)
        ((ushort8*)Wl)[j] = ((const ushort8*)Wp)[j];
    __syncthreads();

    int wave = t >> 6, lane = t & 63;
    int rowtile = blockIdx.x * 256 + wave * 32;
    int ar  = lane & 15;          // A-row within 16-row tile
    int sub = (lane >> 4) * 8;    // k sub-offset (elements) within 32-chunk

    int r0 = rowtile + ar, r1 = r0 + 16;
    int cr0 = min(r0, NNODES - 1), cr1 = min(r1, NNODES - 1);
    int g0 = idx[cr0], g1 = idx[cr1];

    const unsigned short* s0 = state + (size_t)cr0 * 128 + sub;
    const unsigned short* s1 = state + (size_t)cr1 * 128 + sub;
    const unsigned short* f0 = feat  + (size_t)g0  * 128 + sub;
    const unsigned short* f1 = feat  + (size_t)g1  * 128 + sub;

    f32x4 acc[2][8];
    #pragma unroll
    for (int r = 0; r < 2; ++r)
        #pragma unroll
        for (int n = 0; n < 8; ++n)
            acc[r][n] = f32x4{0.f, 0.f, 0.f, 0.f};

    #pragma unroll
    for (int kk = 0; kk < 8; ++kk) {
        const unsigned short* p0 = (kk < 4) ? s0 + kk * 32 : f0 + (kk - 4) * 32;
        const unsigned short* p1 = (kk < 4) ? s1 + kk * 32 : f1 + (kk - 4) * 32;
        bf16x8 a0 = *(const bf16x8*)p0;
        bf16x8 a1 = *(const bf16x8*)p1;
        #pragma unroll
        for (int n = 0; n < 8; ++n) {
            bf16x8 b = *(const bf16x8*)&Wl[(size_t)((kk * 8 + n) * 64 + lane) * 8];
            acc[0][n] = __builtin_amdgcn_mfma_f32_16x16x32_bf16(a0, b, acc[0][n], 0, 0, 0);
            acc[1][n] = __builtin_amdgcn_mfma_f32_16x16x32_bf16(a1, b, acc[1][n], 0, 0, 0);
        }
    }

    // epilogue: C/D layout col = lane&15, row = (lane>>4)*4 + i   [m89-verified]
    int crow = (lane >> 4) * 4;
    int ccol = lane & 15;
    #pragma unroll
    for (int n = 0; n < 8; ++n) {
        float bv = bias[n * 16 + ccol];
        #pragma unroll
        for (int r = 0; r < 2; ++r) {
            int rb = rowtile + r * 16 + crow;
            #pragma unroll
            for (int i = 0; i < 4; ++i) {
                int row = rb + i;
                if (row < NNODES) {
                    float v = acc[r][n][i] + bv;
                    size_t off = (size_t)row * 128 + n * 16 + ccol;
                    if (FINAL) out_f[off] = fmaxf(v, 0.f);
                    else       out_b[off] = f2bf(v);
                }
            }
        }
    }
}

extern "C" void kernel_launch(void* const* d_in, const int* in_sizes, int n_in,
                              void* d_out, int out_size, void* d_ws, size_t ws_size,
                              hipStream_t stream) {
    const float* feature = (const float*)d_in[0];   // [N][128] fp32
    const float* W       = (const float*)d_in[1];   // [256][128] fp32
    const float* bias    = (const float*)d_in[2];   // [128] fp32
    const int*   idx     = (const int*)d_in[3];     // [3][N] int32

    // workspace layout (needs ~256.07 MB):
    //   Wp        : ws + 0        (64 KB, packed bf16 W)
    //   feature_b : ws + 64 KB    (128 MB bf16 feature table)
    //   s2        : ws + 64KB+128MB (128 MB bf16 hop-1 state)
    // hop-0 state output lives in d_out's first 128 MB (d_out is 256 MB fp32).
    unsigned short* Wp        = (unsigned short*)d_ws;
    unsigned short* feature_b = (unsigned short*)((char*)d_ws + 65536);
    unsigned short* s2        = (unsigned short*)((char*)d_ws + 65536 + (size_t)NNODES * 128 * 2);
    unsigned short* s1        = (unsigned short*)d_out;   // scratch inside d_out
    float*          outf      = (float*)d_out;

    const int nchunk8 = NNODES * DFEAT / 8;   // 8,000,000
    cvt_bf16_kernel<<<2048, 256, 0, stream>>>(feature, feature_b, nchunk8);
    pack_w_kernel<<<16, 256, 0, stream>>>(W, Wp);

    const int grid = (NNODES + 255) / 256;    // 1954 blocks of 512 threads
    hop_kernel<0><<<grid, 512, 0, stream>>>(feature_b, feature_b, idx,              Wp, bias, s1, nullptr);
    hop_kernel<0><<<grid, 512, 0, stream>>>(s1,        feature_b, idx + NNODES,     Wp, bias, s2, nullptr);
    hop_kernel<1><<<grid, 512, 0, stream>>>(s2,        feature_b, idx + 2 * NNODES, Wp, bias, nullptr, outf);
}

// Round 4
// 668.260 us; speedup vs baseline: 1.3284x; 1.1354x over previous
//
#include <hip/hip_runtime.h>
#include <hip/hip_bf16.h>

#define NNODES 500000
#define DFEAT  128   // D
// K = 2*D = 256

typedef __attribute__((ext_vector_type(8))) short    bf16x8;   // MFMA A/B frag (4 VGPRs)
typedef __attribute__((ext_vector_type(4))) float    f32x4;    // MFMA C/D frag
typedef __attribute__((ext_vector_type(4))) float    float4v;
typedef __attribute__((ext_vector_type(8))) unsigned short ushort8;

static __device__ __forceinline__ unsigned short f2bf(float f) {
    unsigned u = __builtin_bit_cast(unsigned, f);
    unsigned r = u + 0x7FFF + ((u >> 16) & 1);   // round-to-nearest-even
    return (unsigned short)(r >> 16);
}

// ---- feature fp32 -> bf16, vectorized (32B in / 16B out per iter) ----
__global__ void cvt_bf16_kernel(const float* __restrict__ in,
                                unsigned short* __restrict__ out, int nchunk8) {
    int i = blockIdx.x * blockDim.x + threadIdx.x;
    int stride = gridDim.x * blockDim.x;
    for (; i < nchunk8; i += stride) {
        float4v a = ((const float4v*)in)[2 * i];
        float4v b = ((const float4v*)in)[2 * i + 1];
        ushort8 o;
        o[0] = f2bf(a.x); o[1] = f2bf(a.y); o[2] = f2bf(a.z); o[3] = f2bf(a.w);
        o[4] = f2bf(b.x); o[5] = f2bf(b.y); o[6] = f2bf(b.z); o[7] = f2bf(b.w);
        ((ushort8*)out)[i] = o;
    }
}

// ---- pack W [256][128] fp32 row-major -> bf16 B-fragment layout ----
// chunk c = (kk*8 + n)*64 + lane ; element i -> B[k = kk*32 + (lane>>4)*8 + i]
//                                               [actual col = (lane&15)*8 + n]
// Column permutation: MFMA tile-col c (= lane&15) of n-tile n maps to actual
// output column c*8 + n, so each lane's 8 n-values are 8 ADJACENT columns ->
// contiguous 16-B (bf16) / 32-B (fp32) stores in the epilogue.
__global__ void pack_w_kernel(const float* __restrict__ W,
                              unsigned short* __restrict__ Wp) {
    int c = blockIdx.x * blockDim.x + threadIdx.x;
    if (c >= 4096) return;
    int l  = c & 63;
    int t  = c >> 6;          // kk*8 + n
    int kk = t >> 3, n = t & 7;
    ushort8 o;
    #pragma unroll
    for (int i = 0; i < 8; ++i) {
        int k   = kk * 32 + (l >> 4) * 8 + i;
        int col = (l & 15) * 8 + n;
        o[i] = f2bf(W[k * 128 + col]);
    }
    ((ushort8*)Wp)[c] = o;
}

// ---- one hop: out = [state | feat[idx]] @ W + b  (ReLU if FINAL) ----
// block = 512 threads (8 waves), each wave owns ONE 16-row MFMA tile so the
// accumulator is only 32 VGPRs and ALL 8 A-fragment loads (+idx) front-load
// into registers before the MFMA loop -> max memory-level parallelism.
// W (64KB bf16, packed) in LDS; 2 blocks/CU = 16 waves/CU.
template<int FINAL>
__global__ __launch_bounds__(512, 4) void hop_kernel(
    const unsigned short* __restrict__ state,   // [N][128] bf16
    const unsigned short* __restrict__ feat,    // [N][128] bf16
    const int*            __restrict__ idx,     // [N]
    const unsigned short* __restrict__ Wp,      // packed, 32768 bf16
    const float*          __restrict__ bias,    // [128]
    unsigned short*       __restrict__ out_b,   // bf16 out (hops 0,1)
    float*                __restrict__ out_f)   // fp32 out (final hop)
{
    __shared__ __align__(16) unsigned short Wl[32768];   // 64 KB
    int t = threadIdx.x;
    int wave = t >> 6, lane = t & 63;
    int rowtile = blockIdx.x * 128 + wave * 16;
    int ar  = lane & 15;          // A-row within 16-row tile
    int sub = (lane >> 4) * 8;    // k sub-offset (elements) within 32-chunk

    int r0  = rowtile + ar;
    int cr0 = min(r0, NNODES - 1);
    int gi  = idx[cr0];           // issue idx gather FIRST (hides under staging)

    // stage W into LDS (independent of idx/A loads)
    for (int j = t; j < 4096; j += 512)
        ((ushort8*)Wl)[j] = ((const ushort8*)Wp)[j];

    // front-load all 8 A fragments (4 state k-chunks + 4 gathered k-chunks)
    const unsigned short* s0 = state + (size_t)cr0 * 128 + sub;
    const unsigned short* f0 = feat  + (size_t)gi  * 128 + sub;
    bf16x8 A[8];
    #pragma unroll
    for (int kk = 0; kk < 4; ++kk) A[kk]     = *(const bf16x8*)(s0 + kk * 32);
    #pragma unroll
    for (int kk = 0; kk < 4; ++kk) A[4 + kk] = *(const bf16x8*)(f0 + kk * 32);

    __syncthreads();

    f32x4 acc[8];
    #pragma unroll
    for (int n = 0; n < 8; ++n) acc[n] = f32x4{0.f, 0.f, 0.f, 0.f};

    #pragma unroll
    for (int kk = 0; kk < 8; ++kk) {
        #pragma unroll
        for (int n = 0; n < 8; ++n) {
            bf16x8 b = *(const bf16x8*)&Wl[(size_t)((kk * 8 + n) * 64 + lane) * 8];
            acc[n] = __builtin_amdgcn_mfma_f32_16x16x32_bf16(A[kk], b, acc[n], 0, 0, 0);
        }
    }

    // epilogue: C/D layout tile-col = lane&15, row = (lane>>4)*4 + i.
    // With the packed column permutation, this lane's 8 n-values are actual
    // columns ccol*8 .. ccol*8+7 -> fully contiguous stores.
    int crow = (lane >> 4) * 4;
    int ccol = lane & 15;
    float4v b0 = *(const float4v*)&bias[ccol * 8];
    float4v b1 = *(const float4v*)&bias[ccol * 8 + 4];
    #pragma unroll
    for (int i = 0; i < 4; ++i) {
        int row = rowtile + crow + i;
        if (row < NNODES) {
            float v0 = acc[0][i] + b0.x, v1 = acc[1][i] + b0.y;
            float v2 = acc[2][i] + b0.z, v3 = acc[3][i] + b0.w;
            float v4 = acc[4][i] + b1.x, v5 = acc[5][i] + b1.y;
            float v6 = acc[6][i] + b1.z, v7 = acc[7][i] + b1.w;
            size_t off = (size_t)row * 128 + ccol * 8;
            if (FINAL) {
                float4v o0 = {fmaxf(v0, 0.f), fmaxf(v1, 0.f), fmaxf(v2, 0.f), fmaxf(v3, 0.f)};
                float4v o1 = {fmaxf(v4, 0.f), fmaxf(v5, 0.f), fmaxf(v6, 0.f), fmaxf(v7, 0.f)};
                *(float4v*)&out_f[off]     = o0;
                *(float4v*)&out_f[off + 4] = o1;
            } else {
                ushort8 o;
                o[0] = f2bf(v0); o[1] = f2bf(v1); o[2] = f2bf(v2); o[3] = f2bf(v3);
                o[4] = f2bf(v4); o[5] = f2bf(v5); o[6] = f2bf(v6); o[7] = f2bf(v7);
                *(ushort8*)&out_b[off] = o;
            }
        }
    }
}

extern "C" void kernel_launch(void* const* d_in, const int* in_sizes, int n_in,
                              void* d_out, int out_size, void* d_ws, size_t ws_size,
                              hipStream_t stream) {
    const float* feature = (const float*)d_in[0];   // [N][128] fp32
    const float* W       = (const float*)d_in[1];   // [256][128] fp32
    const float* bias    = (const float*)d_in[2];   // [128] fp32
    const int*   idx     = (const int*)d_in[3];     // [3][N] int32

    // workspace layout (needs ~256.07 MB):
    //   Wp        : ws + 0        (64 KB, packed bf16 W)
    //   feature_b : ws + 64 KB    (128 MB bf16 feature table)
    //   s2        : ws + 64KB+128MB (128 MB bf16 hop-1 state)
    // hop-0 state output lives in d_out's first 128 MB (d_out is 256 MB fp32).
    unsigned short* Wp        = (unsigned short*)d_ws;
    unsigned short* feature_b = (unsigned short*)((char*)d_ws + 65536);
    unsigned short* s2        = (unsigned short*)((char*)d_ws + 65536 + (size_t)NNODES * 128 * 2);
    unsigned short* s1        = (unsigned short*)d_out;   // scratch inside d_out
    float*          outf      = (float*)d_out;

    const int nchunk8 = NNODES * DFEAT / 8;   // 8,000,000
    cvt_bf16_kernel<<<2048, 256, 0, stream>>>(feature, feature_b, nchunk8);
    pack_w_kernel<<<16, 256, 0, stream>>>(W, Wp);

    const int grid = (NNODES + 127) / 128;    // 3907 blocks of 512 threads
    hop_kernel<0><<<grid, 512, 0, stream>>>(feature_b, feature_b, idx,              Wp, bias, s1, nullptr);
    hop_kernel<0><<<grid, 512, 0, stream>>>(s1,        feature_b, idx + NNODES,     Wp, bias, s2, nullptr);
    hop_kernel<1><<<grid, 512, 0, stream>>>(s2,        feature_b, idx + 2 * NNODES, Wp, bias, nullptr, outf);
}